// Round 10
// baseline (47.906 us; speedup 1.0000x reference)
//
#include <hip/hip_runtime.h>
#include <hip/hip_bf16.h>

// RewardHead fused kernel for MI355X (gfx950) — round 10.
// B=32768, D=64, A=32, K=16, M=128. Output: [B,1] f32.
//
// Diagnosis (R6-R9): main pinned at ~24-26us; 128KB LDS weight staging forces
// 1 block/CU = 2 waves/SIMD; no pipe saturated -> exposed-latency bound.
// vs R9: (a) scalar-dot reassociation — x_t used only in dots (st=x.qW,
// cs=x.wvoc, gs=x.g); attn applied to scalars post-softmax; no bf16 x_t
// pack/unpack, no xpk (-48 VGPR), no xbar; (b) NO LDS weight staging —
// ldB from L2-resident global; 256-thread blocks (4 waves = 2rg x 2mh,
// 16 rows/wave), grid 1024, launch_bounds(256,4) -> 4 blocks/CU,
// 4 waves/SIMD. prep_all byte-identical to R9.

typedef float f32x4 __attribute__((ext_vector_type(4)));
typedef short s16x8 __attribute__((ext_vector_type(8)));

#define OFF_ACTX  0
#define OFF_CTLX  24
#define OFF_CHTX  56
#define OFF_ACTZ  80
#define OFF_CTLZ  84
#define OFF_CHTZ  92
#define OFF_WEQK  96
#define OFF_WVOFT 112
#define N_TILES   128
#define SIG_OFF   (N_TILES*1024)
#define PREP_OFF  (SIG_OFF + 256)

__device__ __forceinline__ unsigned short f2bf(float f){
  unsigned u = __float_as_uint(f);
  u += 0x7fffu + ((u>>16)&1u);          // RNE
  return (unsigned short)(u>>16);
}

union V8 { s16x8 v; unsigned short us[8]; uint4 q; };

__device__ __forceinline__ f32x4 MF(s16x8 a, s16x8 b, f32x4 c){
  return __builtin_amdgcn_mfma_f32_16x16x32_bf16(a, b, c, 0, 0, 0);
}

// B-fragment straight from global (L2-resident 128KB).
__device__ __forceinline__ s16x8 ldB(const unsigned short* __restrict__ pk, int tile, int lane){
  V8 t;
  t.q = *reinterpret_cast<const uint4*>(pk + (((size_t)tile<<6) + lane)*8);
  return t.v;
}

__device__ __forceinline__ s16x8 ldA_g(const float* __restrict__ p, int ko, int limit){
  V8 t;
  if (ko < limit){
    const float4* q4 = reinterpret_cast<const float4*>(p + ko);
    float4 a = q4[0], b = q4[1];
    t.us[0]=f2bf(a.x); t.us[1]=f2bf(a.y); t.us[2]=f2bf(a.z); t.us[3]=f2bf(a.w);
    t.us[4]=f2bf(b.x); t.us[5]=f2bf(b.y); t.us[6]=f2bf(b.z); t.us[7]=f2bf(b.w);
  } else {
    t.q = make_uint4(0u,0u,0u,0u);
  }
  return t.v;
}

__device__ __forceinline__ float tanh_fast(float x){
  x = fminf(15.f, fmaxf(-15.f, x));
  float e = __expf(2.f*x);
  return 1.f - __fdividef(2.f, e + 1.f);
}

// ---------------- prep_all (byte-identical to rounds 6-9) ----------------
__global__ __launch_bounds__(256) void prep_all(
    const float* __restrict__ We, const float* __restrict__ be,
    const float* __restrict__ Wq, const float* __restrict__ Wk,
    const float* __restrict__ Wv, const float* __restrict__ Wo,
    const float* __restrict__ consW, const float* __restrict__ formW,
    const float* __restrict__ aWx, const float* __restrict__ cWx,
    const float* __restrict__ hWx, const float* __restrict__ aWz,
    const float* __restrict__ cWz, const float* __restrict__ hWz,
    unsigned short* __restrict__ packed, float* __restrict__ prep,
    float* __restrict__ sig)
{
  const int b = blockIdx.x;
  const int tid = threadIdx.x;

  if (b < 130){
    __shared__ float Msh[128][129];
    __shared__ float tsh[128];
    if (b <= 64){
      for (int idx = tid; idx < 16384; idx += 256)
        Msh[idx >> 7][idx & 127] = Wk[idx];
      const float* rowv = (b == 64) ? be : (We + (size_t)b*128);
      if (tid < 128){
        float s = 0.f;
        for (int m = 0; m < 128; ++m) s += rowv[m]*Wq[(size_t)m*128 + tid];
        tsh[tid] = s;
      }
      __syncthreads();
      if (tid < 128){
        float s1 = 0.f;
        for (int p = 0; p < 128; ++p) s1 += tsh[p]*Msh[tid][p];
        if (b == 64) prep[16384 + tid] = s1;
        else {
          int r = b;
          int T = OFF_WEQK + ((r>>5)<<3) + (tid>>4);
          int l2 = (((r&31)>>3)<<4) | (tid&15);
          packed[((size_t)T*64 + l2)*8 + (r&7)] = f2bf(s1);
        }
      }
    } else {
      int d = b - 65;
      for (int idx = tid; idx < 16384; idx += 256)
        Msh[idx >> 7][idx & 127] = Wo[idx];
      __syncthreads();
      if (tid < 128){
        float s = 0.f;
        if (d < 64){ for (int j = 0; j < 128; ++j) s += Msh[tid][j]*formW[(size_t)j*64 + d]; }
        else       { for (int j = 0; j < 128; ++j) s += Msh[tid][j]*consW[j]; }
        tsh[tid] = s;
      }
      __syncthreads();
      for (int idx = tid; idx < 16384; idx += 256)
        Msh[idx >> 7][idx & 127] = Wv[idx];
      __syncthreads();
      if (tid < 128){
        float s1 = 0.f;
        for (int p = 0; p < 128; ++p) s1 += Msh[tid][p]*tsh[p];
        if (d < 64){
          int r = d;
          int T = OFF_WVOFT + ((r>>5)<<3) + (tid>>4);
          int l2 = (((r&31)>>3)<<4) | (tid&15);
          packed[((size_t)T*64 + l2)*8 + (r&7)] = f2bf(s1);
        } else prep[16512 + tid] = s1;
      }
    }
    return;
  }

  if (b == 130){
    __shared__ unsigned short SW[8192];
    __shared__ unsigned short SG[4096];

    #pragma unroll
    for (int s4 = 0; s4 < 4; ++s4){
      int q = tid*4 + s4;
      int T = q >> 6, l = q & 63;
      V8 t;
      #pragma unroll
      for (int i = 0; i < 8; ++i){
        int k = (T>>2)*32 + ((l>>4)<<3) + i;
        int n = ((T&3)<<4) + (l&15);
        t.us[i] = f2bf(formW[(size_t)k*64 + n]);
      }
      *reinterpret_cast<uint4*>(&SW[q*8]) = t.q;
    }
    __syncthreads();
    if (tid >= 64) return;
    const int l = tid;
    const f32x4 z4 = {0.f,0.f,0.f,0.f};

    float cs;
    { float c0 = consW[l], c1 = consW[l+64];
      cs = c0*c0 + c1*c1;
      #pragma unroll
      for (int m = 1; m < 64; m <<= 1) cs += __shfl_xor(cs, m);
    }

    s16x8 wf[4][4];
    #pragma unroll
    for (int kt = 0; kt < 4; ++kt)
      #pragma unroll
      for (int x = 0; x < 4; ++x)
        wf[kt][x] = *reinterpret_cast<const s16x8*>(&SW[((((kt<<2)+x)<<6) | l)*8]);

    f32x4 D[4][4];
    #pragma unroll
    for (int it = 0; it < 4; ++it)
      #pragma unroll
      for (int nt = 0; nt < 4; ++nt){
        f32x4 a = z4;
        #pragma unroll
        for (int kt = 0; kt < 4; ++kt) a = MF(wf[kt][it], wf[kt][nt], a);
        D[it][nt] = a;
      }

    float L;
    {
      float ss = 0.f;
      #pragma unroll
      for (int it = 0; it < 4; ++it)
        #pragma unroll
        for (int nt = 0; nt < 4; ++nt)
          #pragma unroll
          for (int j = 0; j < 4; ++j) ss += D[it][nt][j]*D[it][nt][j];
      #pragma unroll
      for (int m = 1; m < 64; m <<= 1) ss += __shfl_xor(ss, m);
      float n0 = sqrtf(ss);
      L = logf(n0);
      float iv = 1.f/n0;
      #pragma unroll
      for (int it = 0; it < 4; ++it){
        int rb  = it*16 + ((l>>4)<<2);
        int lp  = (((rb&31)>>3)<<4) | (l&15);
        int ib  = rb & 7;
        int ktg = rb >> 5;
        #pragma unroll
        for (int nt = 0; nt < 4; ++nt){
          unsigned w0 = (unsigned)f2bf(D[it][nt][0]*iv) | ((unsigned)f2bf(D[it][nt][1]*iv)<<16);
          unsigned w1 = (unsigned)f2bf(D[it][nt][2]*iv) | ((unsigned)f2bf(D[it][nt][3]*iv)<<16);
          uint2 u; u.x = w0; u.y = w1;
          *reinterpret_cast<uint2*>(&SG[((((ktg<<2)+nt)<<6 | lp))*8 + ib]) = u;
        }
      }
    }

    for (int s = 1; s <= 6; ++s){
      s16x8 gf[2][4];
      #pragma unroll
      for (int kt = 0; kt < 2; ++kt)
        #pragma unroll
        for (int x = 0; x < 4; ++x)
          gf[kt][x] = *reinterpret_cast<const s16x8*>(&SG[((((kt<<2)+x)<<6) | l)*8]);
      f32x4 E[4][4];
      #pragma unroll
      for (int it = 0; it < 4; ++it)
        #pragma unroll
        for (int nt = 0; nt < 4; ++nt){
          f32x4 a = MF(gf[0][it], gf[0][nt], z4);
          E[it][nt] = MF(gf[1][it], gf[1][nt], a);
        }
      float ss = 0.f;
      #pragma unroll
      for (int it = 0; it < 4; ++it)
        #pragma unroll
        for (int nt = 0; nt < 4; ++nt)
          #pragma unroll
          for (int j = 0; j < 4; ++j) ss += E[it][nt][j]*E[it][nt][j];
      #pragma unroll
      for (int m = 1; m < 64; m <<= 1) ss += __shfl_xor(ss, m);
      float ns = sqrtf(ss);
      L = 2.f*L + logf(ns);
      if (s < 6){
        float iv = 1.f/ns;
        #pragma unroll
        for (int it = 0; it < 4; ++it){
          int rb  = it*16 + ((l>>4)<<2);
          int lp  = (((rb&31)>>3)<<4) | (l&15);
          int ib  = rb & 7;
          int ktg = rb >> 5;
          #pragma unroll
          for (int nt = 0; nt < 4; ++nt){
            unsigned w0 = (unsigned)f2bf(E[it][nt][0]*iv) | ((unsigned)f2bf(E[it][nt][1]*iv)<<16);
            unsigned w1 = (unsigned)f2bf(E[it][nt][2]*iv) | ((unsigned)f2bf(E[it][nt][3]*iv)<<16);
            uint2 u; u.x = w0; u.y = w1;
            *reinterpret_cast<uint2*>(&SG[((((ktg<<2)+nt)<<6 | lp))*8 + ib]) = u;
          }
        }
      }
    }

    if (l == 0){
      float sf = expf(L*(1.f/128.f));
      sig[0] = 1.f/(sf + 1e-6f);
      sig[1] = 1.f/(sqrtf(cs) + 1e-6f);
    }
    return;
  }

  {
    int tile = b - 131;
    const float* W; int N; int kind = 0; int base;
    if      (tile < 24) { W=aWx; N=128; base=OFF_ACTX; }
    else if (tile < 56) { W=cWx; N=128; base=OFF_CTLX; }
    else if (tile < 80) { W=hWx; N=128; base=OFF_CHTX; kind=1; }
    else if (tile < 84) { W=aWz; N=64;  base=OFF_ACTZ; }
    else if (tile < 92) { W=cWz; N=64;  base=OFF_CTLZ; }
    else                { W=hWz; N=64;  base=OFF_CHTZ; kind=2; }
    int NT = N >> 4;
    int lt = tile - base;
    int nt = lt % NT, kt = lt / NT;
    int l = tid >> 2, i0 = (tid & 3)*2;
    unsigned short us2[2];
    #pragma unroll
    for (int di = 0; di < 2; ++di){
      int i = i0 + di;
      int k = kt*32 + ((l>>4)<<3) + i;
      int n = nt*16 + (l & 15);
      int sr = k;
      if (kind == 1) sr = (k < 16) ? k : (k < 32 ? -1 : k - 16);
      else if (kind == 2) sr = (k < 16) ? k : -1;
      float v = (sr >= 0) ? W[(size_t)sr*N + n] : 0.f;
      us2[di] = f2bf(v);
    }
    *reinterpret_cast<unsigned*>(&packed[((size_t)tile*64 + l)*8 + i0]) =
        (unsigned)us2[0] | ((unsigned)us2[1] << 16);
  }
}

// ---------------- scalar-dot tokenizer ----------------
// Computes per-row scalars for this wave's M-half: st (score partial,
// includes -d2 partial), cs (x . wvoc partial), gs (x . g partial).
template<int KTX, int KTZ>
__device__ __forceinline__ void token_dot(
    const unsigned short* __restrict__ pk, int offX, const s16x8* afX,
    int offZ, const s16x8* afZ, const float* __restrict__ bx,
    int lane, int ntb, int nzb,
    const f32x4 qw[4], const f32x4 g[4], const float wv[4],
    float st[4], float cs[4], float gs[4])
{
  const int r15 = lane & 15;
  const f32x4 z4 = {0.f,0.f,0.f,0.f};
  f32x4 acc[4];
  #pragma unroll
  for (int nl = 0; nl < 4; ++nl) acc[nl] = z4;
  #pragma unroll
  for (int kt = 0; kt < KTX; ++kt)
    #pragma unroll
    for (int nl = 0; nl < 4; ++nl)
      acc[nl] = MF(afX[kt], ldB(pk, offX + kt*8 + ntb + nl, lane), acc[nl]);

  float qs[4] = {0.f,0.f,0.f,0.f};
  float cp[4] = {0.f,0.f,0.f,0.f};
  float gp[4] = {0.f,0.f,0.f,0.f};
  #pragma unroll
  for (int nl = 0; nl < 4; ++nl){
    float bv = bx[(ntb + nl)*16 + r15];
    #pragma unroll
    for (int j = 0; j < 4; ++j){
      float x = tanh_fast(acc[nl][j] + bv);
      qs[j] += x*qw[nl][j];
      cp[j] += x*wv[nl];
      gp[j] += x*g[nl][j];
    }
  }

  // dist2 partial (this wave's 2 of 4 Wz tiles)
  f32x4 a2[2];
  a2[0] = z4; a2[1] = z4;
  #pragma unroll
  for (int kt = 0; kt < KTZ; ++kt)
    #pragma unroll
    for (int nl = 0; nl < 2; ++nl)
      a2[nl] = MF(afZ[kt], ldB(pk, offZ + kt*4 + nzb + nl, lane), a2[nl]);

  const float isq = 0.0883883476483184f;
  #pragma unroll
  for (int j = 0; j < 4; ++j){
    float t0 = tanh_fast(a2[0][j]);
    float t1 = tanh_fast(a2[1][j]);
    st[j] = qs[j]*isq - (t0*t0 + t1*t1);
    cs[j] = cp[j];
    gs[j] = gp[j];
  }
}

// ---------------- main kernel: 4 waves = 2 row-groups x 2 M-halves ----------------
// No LDS weight staging; B-frags from L2. 1024 blocks x 256 threads;
// launch_bounds(256,4) -> 4 blocks/CU, 4 waves/SIMD.
__global__ __launch_bounds__(256, 4) void reward_main(
    const float* __restrict__ z, const float* __restrict__ action,
    const float* __restrict__ rw, const float* __restrict__ control,
    const float* __restrict__ act_bx, const float* __restrict__ ctl_bx,
    const float* __restrict__ cht_bx, const float* __restrict__ consb,
    const float* __restrict__ formb,
    const unsigned short* __restrict__ packed, const float* __restrict__ prep,
    const float* __restrict__ sig, float* __restrict__ out)
{
  __shared__ float exS[2][2][3][16];   // rg, mh, t, row
  __shared__ float exT[2][2][16];      // rg, mh, row

  const int tid  = threadIdx.x;
  const int wid  = tid >> 6;
  const int lane = tid & 63;
  const int rg   = wid >> 1;
  const int mh   = wid & 1;
  const int g0   = blockIdx.x*32 + rg*16;
  const int r15  = lane & 15;
  const int hi   = lane >> 4;
  const int ko   = hi << 3;
  const int rb   = hi << 2;
  const int arow = g0 + r15;
  const int ntb  = mh << 2;
  const int nzb  = mh << 1;
  const f32x4 z4 = {0.f,0.f,0.f,0.f};

  // ---- raw-input A-fragments ----
  s16x8 fz0 = ldA_g(z + (size_t)arow*64,            ko, 64);
  s16x8 fz1 = ldA_g(z + (size_t)arow*64 + 32,       ko, 32);
  s16x8 fac = ldA_g(action + (size_t)arow*32,       ko, 32);
  s16x8 fc0 = ldA_g(control + (size_t)arow*64,      ko, 64);
  s16x8 fc1 = ldA_g(control + (size_t)arow*64 + 32, ko, 32);
  s16x8 frw = ldA_g(rw + (size_t)arow*16,           ko, 16);

  // ---- qW half ----
  f32x4 qw[4];
  {
    #pragma unroll
    for (int nl = 0; nl < 4; ++nl) qw[nl] = z4;
    #pragma unroll
    for (int kt = 0; kt < 2; ++kt)
      #pragma unroll
      for (int nl = 0; nl < 4; ++nl)
        qw[nl] = MF(kt == 0 ? fz0 : fz1, ldB(packed, OFF_WEQK + kt*8 + ntb + nl, lane), qw[nl]);
    const float* bqk = prep + 16384;
    #pragma unroll
    for (int nl = 0; nl < 4; ++nl){
      float bv = bqk[(ntb + nl)*16 + r15];
      #pragma unroll
      for (int j = 0; j < 4; ++j) qw[nl][j] += bv;
    }
  }

  // ---- g half ----
  f32x4 g[4];
  {
    #pragma unroll
    for (int nl = 0; nl < 4; ++nl) g[nl] = z4;
    #pragma unroll
    for (int kt = 0; kt < 2; ++kt)
      #pragma unroll
      for (int nl = 0; nl < 4; ++nl)
        g[nl] = MF(kt == 0 ? fc0 : fc1, ldB(packed, OFF_WVOFT + kt*8 + ntb + nl, lane), g[nl]);
  }

  // ---- wvoc half ----
  const float* wvoc = prep + 16512;
  float wv[4];
  #pragma unroll
  for (int nl = 0; nl < 4; ++nl) wv[nl] = wvoc[(ntb + nl)*16 + r15];

  // ---- tokens: per-row scalars only ----
  float st[3][4], cs[3][4], gs[3][4];
  {
    s16x8 afA[3] = {fac, fz0, fz1};
    token_dot<3,1>(packed, OFF_ACTX, afA, OFF_ACTZ, &fac, act_bx, lane, ntb, nzb,
                   qw, g, wv, st[0], cs[0], gs[0]);
  }
  {
    s16x8 afH[3] = {frw, fz0, fz1};
    token_dot<3,1>(packed, OFF_CHTX, afH, OFF_CHTZ, &frw, cht_bx, lane, ntb, nzb,
                   qw, g, wv, st[2], cs[2], gs[2]);
  }
  {
    s16x8 afC[4] = {fc0, fc1, fz0, fz1};
    s16x8 afCz[2] = {fc0, fc1};
    token_dot<4,2>(packed, OFF_CTLX, afC, OFF_CTLZ, afCz, ctl_bx, lane, ntb, nzb,
                   qw, g, wv, st[1], cs[1], gs[1]);
  }

  // ---- reduce st over the 16-lane M-sweep ----
  #pragma unroll
  for (int m = 1; m < 16; m <<= 1)
    #pragma unroll
    for (int t = 0; t < 3; ++t)
      #pragma unroll
      for (int j = 0; j < 4; ++j) st[t][j] += __shfl_xor(st[t][j], m);

  if (r15 == 0){
    #pragma unroll
    for (int t = 0; t < 3; ++t)
      #pragma unroll
      for (int j = 0; j < 4; ++j) exS[rg][mh][t][rb+j] = st[t][j];
  }
  __syncthreads();

  // ---- softmax over 3 tokens (merge M-halves) ----
  float at[3][4];
  #pragma unroll
  for (int j = 0; j < 4; ++j){
    int r = rb + j;
    float s0 = exS[rg][0][0][r] + exS[rg][1][0][r];
    float s1 = exS[rg][0][1][r] + exS[rg][1][1][r];
    float s2 = exS[rg][0][2][r] + exS[rg][1][2][r];
    float mx = fmaxf(s0, fmaxf(s1, s2));
    float e0 = __expf(s0 - mx), e1 = __expf(s1 - mx), e2 = __expf(s2 - mx);
    float inv = 1.f/(e0 + e1 + e2);
    at[0][j] = e0*inv; at[1][j] = e1*inv; at[2][j] = e2*inv;
  }

  // ---- combine scalars with attn, then one reduce ----
  const float inv_f = sig[0], inv_c = sig[1], cb = consb[0];
  float tot[4];
  #pragma unroll
  for (int j = 0; j < 4; ++j){
    float sc = at[0][j]*cs[0][j] + at[1][j]*cs[1][j] + at[2][j]*cs[2][j];
    float sg = at[0][j]*gs[0][j] + at[1][j]*gs[1][j] + at[2][j]*gs[2][j];
    tot[j] = inv_c*sc + inv_f*sg;
  }
  #pragma unroll
  for (int m = 1; m < 16; m <<= 1)
    #pragma unroll
    for (int j = 0; j < 4; ++j) tot[j] += __shfl_xor(tot[j], m);

  if (r15 == 0){
    #pragma unroll
    for (int j = 0; j < 4; ++j) exT[rg][mh][rb+j] = tot[j];
  }
  __syncthreads();

  if (mh == 0){
    // ---- fb . control (f32 reload, L1/L2 hot) ----
    float fbp;
    {
      const float* cp = control + (size_t)arow*64;
      float4 c0a = *(const float4*)(cp + ko);
      float4 c0b = *(const float4*)(cp + ko + 4);
      float4 c1a = *(const float4*)(cp + 32 + ko);
      float4 c1b = *(const float4*)(cp + 32 + ko + 4);
      float4 f0a = *(const float4*)(formb + ko);
      float4 f0b = *(const float4*)(formb + ko + 4);
      float4 f1a = *(const float4*)(formb + 32 + ko);
      float4 f1b = *(const float4*)(formb + 32 + ko + 4);
      fbp = c0a.x*f0a.x + c0a.y*f0a.y + c0a.z*f0a.z + c0a.w*f0a.w
          + c0b.x*f0b.x + c0b.y*f0b.y + c0b.z*f0b.z + c0b.w*f0b.w
          + c1a.x*f1a.x + c1a.y*f1a.y + c1a.z*f1a.z + c1a.w*f1a.w
          + c1b.x*f1b.x + c1b.y*f1b.y + c1b.z*f1b.z + c1b.w*f1b.w;
    }
    fbp += __shfl_xor(fbp, 16);
    fbp += __shfl_xor(fbp, 32);

    float fbj[4];
    #pragma unroll
    for (int j = 0; j < 4; ++j) fbj[j] = __shfl(fbp, hi*4 + j);
    if (r15 == 0){
      #pragma unroll
      for (int j = 0; j < 4; ++j){
        int r = rb + j;
        out[g0 + r] = exT[rg][0][r] + exT[rg][1][r] + fbj[j] + cb;
      }
    }
  }
}

extern "C" void kernel_launch(void* const* d_in, const int* in_sizes, int n_in,
                              void* d_out, int out_size, void* d_ws, size_t ws_size,
                              hipStream_t stream)
{
  const float* z      = (const float*)d_in[0];
  const float* action = (const float*)d_in[1];
  const float* rw     = (const float*)d_in[2];
  const float* control= (const float*)d_in[3];
  const float* actWx  = (const float*)d_in[4];
  const float* actbx  = (const float*)d_in[5];
  const float* actWz  = (const float*)d_in[6];
  const float* ctlWx  = (const float*)d_in[7];
  const float* ctlbx  = (const float*)d_in[8];
  const float* ctlWz  = (const float*)d_in[9];
  const float* chtWx  = (const float*)d_in[10];
  const float* chtbx  = (const float*)d_in[11];
  const float* chtWz  = (const float*)d_in[12];
  const float* We     = (const float*)d_in[13];
  const float* be     = (const float*)d_in[14];
  const float* Wq     = (const float*)d_in[15];
  const float* Wk     = (const float*)d_in[16];
  const float* Wv     = (const float*)d_in[17];
  const float* Wo     = (const float*)d_in[18];
  const float* consW  = (const float*)d_in[19];
  const float* consb  = (const float*)d_in[20];
  const float* formW  = (const float*)d_in[21];
  const float* formb  = (const float*)d_in[22];
  float* out = (float*)d_out;

  unsigned short* packed = (unsigned short*)d_ws;
  float* sig  = (float*)((char*)d_ws + SIG_OFF);
  float* prep = (float*)((char*)d_ws + PREP_OFF);

  hipLaunchKernelGGL(prep_all, dim3(227), dim3(256), 0, stream,
                     We, be, Wq, Wk, Wv, Wo, consW, formW,
                     actWx, ctlWx, chtWx, actWz, ctlWz, chtWz,
                     packed, prep, sig);
  hipLaunchKernelGGL(reward_main, dim3(1024), dim3(256), 0, stream,
                     z, action, rw, control, actbx, ctlbx, chtbx,
                     consb, formb, packed, prep, sig, out);
}

// Round 11
// 33.063 us; speedup vs baseline: 1.4489x; 1.4489x over previous
//
#include <hip/hip_runtime.h>
#include <hip/hip_bf16.h>

// RewardHead fused kernel for MI355X (gfx950) — round 11.
// B=32768, D=64, A=32, K=16, M=128. Output: [B,1] f32.
//
// R10 lesson: L2-direct B-reads cost +9us -> keep LDS staging (R9 geometry:
// 512 thr, 8 waves = 4 rg(32 rows) x 2 mh). R2 profile re-read: VALUBusy
// 24.8% x 77.9us => kernel is VALU-ISSUE-bound; this round is the diet:
//  - tanh = 1 - 2*rcp(exp(2x)+1): 5 ops, saturates naturally (no clamp).
//  - v_cvt_pk_bf16_f32 inline asm for f32->bf16 (1 instr / 2 elems, RNE).
//  - global_load_lds (width 16) for the 128KB weight staging (async DMA).
//  - scalar-dot (R10): st/hs per token; hs folds inv_c*wvoc + inv_f*g.
//  - 2-step shfl + one [128][49] LDS exchange + 128-thread merge phase
//    (softmax+epilogue+store); 2 barriers total.
// prep_all: split-K folds (two 128-thread halves) + float4 staging.

typedef float f32x4 __attribute__((ext_vector_type(4)));
typedef short s16x8 __attribute__((ext_vector_type(8)));

#define OFF_ACTX  0
#define OFF_CTLX  24
#define OFF_CHTX  56
#define OFF_ACTZ  80
#define OFF_CTLZ  84
#define OFF_CHTZ  92
#define OFF_WEQK  96
#define OFF_WVOFT 112
#define N_TILES   128
#define SIG_OFF   (N_TILES*1024)
#define PREP_OFF  (SIG_OFF + 256)

__device__ __forceinline__ unsigned short f2bf(float f){
  unsigned u = __float_as_uint(f);
  u += 0x7fffu + ((u>>16)&1u);          // RNE (prep only)
  return (unsigned short)(u>>16);
}

// HW packed f32->bf16 (RNE), 2 elems per instruction.
__device__ __forceinline__ unsigned cvtpk(float lo, float hi){
  unsigned r;
  asm("v_cvt_pk_bf16_f32 %0, %1, %2" : "=v"(r) : "v"(lo), "v"(hi));
  return r;
}

union V8 { s16x8 v; unsigned short us[8]; uint4 q; };

__device__ __forceinline__ f32x4 MF(s16x8 a, s16x8 b, f32x4 c){
  return __builtin_amdgcn_mfma_f32_16x16x32_bf16(a, b, c, 0, 0, 0);
}

__device__ __forceinline__ s16x8 ldB(const unsigned short* pk, int tile, int lane){
  V8 t;
  t.q = *reinterpret_cast<const uint4*>(pk + ((tile<<6) + lane)*8);
  return t.v;
}

__device__ __forceinline__ s16x8 ldA_g(const float* __restrict__ p, int ko, int limit){
  V8 t;
  if (ko < limit){
    const float4* q4 = reinterpret_cast<const float4*>(p + ko);
    float4 a = q4[0], b = q4[1];
    t.q = make_uint4(cvtpk(a.x,a.y), cvtpk(a.z,a.w), cvtpk(b.x,b.y), cvtpk(b.z,b.w));
  } else {
    t.q = make_uint4(0u,0u,0u,0u);
  }
  return t.v;
}

// 5-op tanh: saturates via inf/0 (x>>0: exp=inf -> rcp=0 -> 1; x<<0: -1).
__device__ __forceinline__ float tanh_fast(float x){
  float e = __expf(2.f*x);
  return 1.f - 2.f*__builtin_amdgcn_rcpf(e + 1.f);
}

// ---------------- prep_all: split-K folds + sigma + pack ----------------
__global__ __launch_bounds__(256) void prep_all(
    const float* __restrict__ We, const float* __restrict__ be,
    const float* __restrict__ Wq, const float* __restrict__ Wk,
    const float* __restrict__ Wv, const float* __restrict__ Wo,
    const float* __restrict__ consW, const float* __restrict__ formW,
    const float* __restrict__ aWx, const float* __restrict__ cWx,
    const float* __restrict__ hWx, const float* __restrict__ aWz,
    const float* __restrict__ cWz, const float* __restrict__ hWz,
    unsigned short* __restrict__ packed, float* __restrict__ prep,
    float* __restrict__ sig)
{
  const int b = blockIdx.x;
  const int tid = threadIdx.x;

  if (b < 130){
    __shared__ float Msh[128][129];
    __shared__ float tsh[128];
    __shared__ float ph[2][128];
    const int half = tid >> 7, t128 = tid & 127;
    const int m0 = half*64;
    if (b <= 64){
      // stage Wk (float4 global loads)
      for (int i4 = tid; i4 < 4096; i4 += 256){
        float4 v = ((const float4*)Wk)[i4];
        int r = i4 >> 5, c = (i4 & 31) << 2;
        Msh[r][c] = v.x; Msh[r][c+1] = v.y; Msh[r][c+2] = v.z; Msh[r][c+3] = v.w;
      }
      const float* rowv = (b == 64) ? be : (We + (size_t)b*128);
      {
        float s = 0.f;
        for (int m = m0; m < m0+64; ++m) s += rowv[m]*Wq[(size_t)m*128 + t128];
        ph[half][t128] = s;
      }
      __syncthreads();
      if (tid < 128) tsh[tid] = ph[0][tid] + ph[1][tid];
      __syncthreads();
      {
        float s1 = 0.f;
        for (int p = m0; p < m0+64; ++p) s1 += tsh[p]*Msh[t128][p];
        ph[half][t128] = s1;
      }
      __syncthreads();
      if (tid < 128){
        float s1 = ph[0][tid] + ph[1][tid];
        if (b == 64) prep[16384 + tid] = s1;
        else {
          int r = b;
          int T = OFF_WEQK + ((r>>5)<<3) + (tid>>4);
          int l2 = (((r&31)>>3)<<4) | (tid&15);
          packed[((size_t)T*64 + l2)*8 + (r&7)] = f2bf(s1);
        }
      }
    } else {
      int d = b - 65;                        // 0..63: WvofT row d; 64: wvoc
      for (int i4 = tid; i4 < 4096; i4 += 256){
        float4 v = ((const float4*)Wo)[i4];
        int r = i4 >> 5, c = (i4 & 31) << 2;
        Msh[r][c] = v.x; Msh[r][c+1] = v.y; Msh[r][c+2] = v.z; Msh[r][c+3] = v.w;
      }
      __syncthreads();
      {
        float s = 0.f;
        if (d < 64){ for (int j = m0; j < m0+64; ++j) s += Msh[t128][j]*formW[(size_t)j*64 + d]; }
        else       { for (int j = m0; j < m0+64; ++j) s += Msh[t128][j]*consW[j]; }
        ph[half][t128] = s;
      }
      __syncthreads();
      if (tid < 128) tsh[tid] = ph[0][tid] + ph[1][tid];
      __syncthreads();
      for (int i4 = tid; i4 < 4096; i4 += 256){
        float4 v = ((const float4*)Wv)[i4];
        int r = i4 >> 5, c = (i4 & 31) << 2;
        Msh[r][c] = v.x; Msh[r][c+1] = v.y; Msh[r][c+2] = v.z; Msh[r][c+3] = v.w;
      }
      __syncthreads();
      {
        float s1 = 0.f;
        for (int p = m0; p < m0+64; ++p) s1 += Msh[t128][p]*tsh[p];
        ph[half][t128] = s1;
      }
      __syncthreads();
      if (tid < 128){
        float s1 = ph[0][tid] + ph[1][tid];
        if (d < 64){
          int r = d;
          int T = OFF_WVOFT + ((r>>5)<<3) + (tid>>4);
          int l2 = (((r&31)>>3)<<4) | (tid&15);
          packed[((size_t)T*64 + l2)*8 + (r&7)] = f2bf(s1);
        } else prep[16512 + tid] = s1;
      }
    }
    return;
  }

  if (b == 130){
    // ---- spectral norms: 1-wave MFMA squaring chain (unchanged) ----
    __shared__ unsigned short SW[8192];
    __shared__ unsigned short SG[4096];

    #pragma unroll
    for (int s4 = 0; s4 < 4; ++s4){
      int q = tid*4 + s4;
      int T = q >> 6, l = q & 63;
      V8 t;
      #pragma unroll
      for (int i = 0; i < 8; ++i){
        int k = (T>>2)*32 + ((l>>4)<<3) + i;
        int n = ((T&3)<<4) + (l&15);
        t.us[i] = f2bf(formW[(size_t)k*64 + n]);
      }
      *reinterpret_cast<uint4*>(&SW[q*8]) = t.q;
    }
    __syncthreads();
    if (tid >= 64) return;
    const int l = tid;
    const f32x4 z4 = {0.f,0.f,0.f,0.f};

    float cs;
    { float c0 = consW[l], c1 = consW[l+64];
      cs = c0*c0 + c1*c1;
      #pragma unroll
      for (int m = 1; m < 64; m <<= 1) cs += __shfl_xor(cs, m);
    }

    s16x8 wf[4][4];
    #pragma unroll
    for (int kt = 0; kt < 4; ++kt)
      #pragma unroll
      for (int x = 0; x < 4; ++x)
        wf[kt][x] = *reinterpret_cast<const s16x8*>(&SW[((((kt<<2)+x)<<6) | l)*8]);

    f32x4 D[4][4];
    #pragma unroll
    for (int it = 0; it < 4; ++it)
      #pragma unroll
      for (int nt = 0; nt < 4; ++nt){
        f32x4 a = z4;
        #pragma unroll
        for (int kt = 0; kt < 4; ++kt) a = MF(wf[kt][it], wf[kt][nt], a);
        D[it][nt] = a;
      }

    float L;
    {
      float ss = 0.f;
      #pragma unroll
      for (int it = 0; it < 4; ++it)
        #pragma unroll
        for (int nt = 0; nt < 4; ++nt)
          #pragma unroll
          for (int j = 0; j < 4; ++j) ss += D[it][nt][j]*D[it][nt][j];
      #pragma unroll
      for (int m = 1; m < 64; m <<= 1) ss += __shfl_xor(ss, m);
      float n0 = sqrtf(ss);
      L = logf(n0);
      float iv = 1.f/n0;
      #pragma unroll
      for (int it = 0; it < 4; ++it){
        int rb  = it*16 + ((l>>4)<<2);
        int lp  = (((rb&31)>>3)<<4) | (l&15);
        int ib  = rb & 7;
        int ktg = rb >> 5;
        #pragma unroll
        for (int nt = 0; nt < 4; ++nt){
          unsigned w0 = (unsigned)f2bf(D[it][nt][0]*iv) | ((unsigned)f2bf(D[it][nt][1]*iv)<<16);
          unsigned w1 = (unsigned)f2bf(D[it][nt][2]*iv) | ((unsigned)f2bf(D[it][nt][3]*iv)<<16);
          uint2 u; u.x = w0; u.y = w1;
          *reinterpret_cast<uint2*>(&SG[((((ktg<<2)+nt)<<6 | lp))*8 + ib]) = u;
        }
      }
    }

    for (int s = 1; s <= 6; ++s){
      s16x8 gf[2][4];
      #pragma unroll
      for (int kt = 0; kt < 2; ++kt)
        #pragma unroll
        for (int x = 0; x < 4; ++x)
          gf[kt][x] = *reinterpret_cast<const s16x8*>(&SG[((((kt<<2)+x)<<6) | l)*8]);
      f32x4 E[4][4];
      #pragma unroll
      for (int it = 0; it < 4; ++it)
        #pragma unroll
        for (int nt = 0; nt < 4; ++nt){
          f32x4 a = MF(gf[0][it], gf[0][nt], z4);
          E[it][nt] = MF(gf[1][it], gf[1][nt], a);
        }
      float ss = 0.f;
      #pragma unroll
      for (int it = 0; it < 4; ++it)
        #pragma unroll
        for (int nt = 0; nt < 4; ++nt)
          #pragma unroll
          for (int j = 0; j < 4; ++j) ss += E[it][nt][j]*E[it][nt][j];
      #pragma unroll
      for (int m = 1; m < 64; m <<= 1) ss += __shfl_xor(ss, m);
      float ns = sqrtf(ss);
      L = 2.f*L + logf(ns);
      if (s < 6){
        float iv = 1.f/ns;
        #pragma unroll
        for (int it = 0; it < 4; ++it){
          int rb  = it*16 + ((l>>4)<<2);
          int lp  = (((rb&31)>>3)<<4) | (l&15);
          int ib  = rb & 7;
          int ktg = rb >> 5;
          #pragma unroll
          for (int nt = 0; nt < 4; ++nt){
            unsigned w0 = (unsigned)f2bf(E[it][nt][0]*iv) | ((unsigned)f2bf(E[it][nt][1]*iv)<<16);
            unsigned w1 = (unsigned)f2bf(E[it][nt][2]*iv) | ((unsigned)f2bf(E[it][nt][3]*iv)<<16);
            uint2 u; u.x = w0; u.y = w1;
            *reinterpret_cast<uint2*>(&SG[((((ktg<<2)+nt)<<6 | lp))*8 + ib]) = u;
          }
        }
      }
    }

    if (l == 0){
      float sf = expf(L*(1.f/128.f));
      sig[0] = 1.f/(sf + 1e-6f);
      sig[1] = 1.f/(sqrtf(cs) + 1e-6f);
    }
    return;
  }

  // ---- blocks 131..226: pack tokenizer tiles (unchanged) ----
  {
    int tile = b - 131;
    const float* W; int N; int kind = 0; int base;
    if      (tile < 24) { W=aWx; N=128; base=OFF_ACTX; }
    else if (tile < 56) { W=cWx; N=128; base=OFF_CTLX; }
    else if (tile < 80) { W=hWx; N=128; base=OFF_CHTX; kind=1; }
    else if (tile < 84) { W=aWz; N=64;  base=OFF_ACTZ; }
    else if (tile < 92) { W=cWz; N=64;  base=OFF_CTLZ; }
    else                { W=hWz; N=64;  base=OFF_CHTZ; kind=2; }
    int NT = N >> 4;
    int lt = tile - base;
    int nt = lt % NT, kt = lt / NT;
    int l = tid >> 2, i0 = (tid & 3)*2;
    unsigned short us2[2];
    #pragma unroll
    for (int di = 0; di < 2; ++di){
      int i = i0 + di;
      int k = kt*32 + ((l>>4)<<3) + i;
      int n = nt*16 + (l & 15);
      int sr = k;
      if (kind == 1) sr = (k < 16) ? k : (k < 32 ? -1 : k - 16);
      else if (kind == 2) sr = (k < 16) ? k : -1;
      float v = (sr >= 0) ? W[(size_t)sr*N + n] : 0.f;
      us2[di] = f2bf(v);
    }
    *reinterpret_cast<unsigned*>(&packed[((size_t)tile*64 + l)*8 + i0]) =
        (unsigned)us2[0] | ((unsigned)us2[1] << 16);
  }
}

// ---------------- dual-subtile scalar-dot tokenizer ----------------
// st[s][j]: score partial (qs*isq - d2 partial); hs[s][j]: head partial
// x . (inv_c*wvoc + inv_f*g), with hw = that combined vector.
template<int KTX, int KTZ>
__device__ __forceinline__ void token_dot2(
    const unsigned short* pk, int offX, const s16x8 (*afX)[2],
    int offZ, const s16x8 (*afZ)[2], const float* __restrict__ bx,
    int lane, int ntb, int nzb,
    const f32x4 qw[2][4], const f32x4 hw[2][4],
    float st[2][4], float hs[2][4])
{
  const int r15 = lane & 15;
  const f32x4 z4 = {0.f,0.f,0.f,0.f};
  f32x4 acc[2][4];
  #pragma unroll
  for (int s = 0; s < 2; ++s)
    #pragma unroll
    for (int nl = 0; nl < 4; ++nl) acc[s][nl] = z4;
  #pragma unroll
  for (int kt = 0; kt < KTX; ++kt){
    #pragma unroll
    for (int nl = 0; nl < 4; ++nl){
      s16x8 bfr = ldB(pk, offX + kt*8 + ntb + nl, lane);
      acc[0][nl] = MF(afX[kt][0], bfr, acc[0][nl]);
      acc[1][nl] = MF(afX[kt][1], bfr, acc[1][nl]);
    }
  }
  float qs[2][4], hp[2][4];
  #pragma unroll
  for (int s = 0; s < 2; ++s)
    #pragma unroll
    for (int j = 0; j < 4; ++j){ qs[s][j] = 0.f; hp[s][j] = 0.f; }
  #pragma unroll
  for (int nl = 0; nl < 4; ++nl){
    float bv = bx[(ntb + nl)*16 + r15];
    #pragma unroll
    for (int s = 0; s < 2; ++s)
      #pragma unroll
      for (int j = 0; j < 4; ++j){
        float x = tanh_fast(acc[s][nl][j] + bv);
        qs[s][j] += x*qw[s][nl][j];
        hp[s][j] += x*hw[s][nl][j];
      }
  }
  // dist2 partial (this wave's 2 of 4 Wz tiles)
  f32x4 a2[2][2];
  #pragma unroll
  for (int s = 0; s < 2; ++s){ a2[s][0] = z4; a2[s][1] = z4; }
  #pragma unroll
  for (int kt = 0; kt < KTZ; ++kt){
    #pragma unroll
    for (int nl = 0; nl < 2; ++nl){
      s16x8 bfr = ldB(pk, offZ + kt*4 + nzb + nl, lane);
      a2[0][nl] = MF(afZ[kt][0], bfr, a2[0][nl]);
      a2[1][nl] = MF(afZ[kt][1], bfr, a2[1][nl]);
    }
  }
  const float isq = 0.0883883476483184f;
  #pragma unroll
  for (int s = 0; s < 2; ++s)
    #pragma unroll
    for (int j = 0; j < 4; ++j){
      float t0 = tanh_fast(a2[s][0][j]);
      float t1 = tanh_fast(a2[s][1][j]);
      st[s][j] = qs[s][j]*isq - (t0*t0 + t1*t1);
      hs[s][j] = hp[s][j];
    }
}

// ---------------- main: 8 waves = 4 rg(32 rows) x 2 mh; merge phase ----------------
__global__ __launch_bounds__(512, 2) void reward_main(
    const float* __restrict__ z, const float* __restrict__ action,
    const float* __restrict__ rw, const float* __restrict__ control,
    const float* __restrict__ act_bx, const float* __restrict__ ctl_bx,
    const float* __restrict__ cht_bx, const float* __restrict__ consb,
    const float* __restrict__ formb,
    const unsigned short* __restrict__ packed, const float* __restrict__ prep,
    const float* __restrict__ sig, float* __restrict__ out)
{
  __shared__ unsigned short pk_sh[65536];   // 128 KB staged weights
  __shared__ float ex[128][49];             // st(0..23) hs(24..47) fb(48)

  const int tid  = threadIdx.x;
  const int wid  = tid >> 6;
  const int lane = tid & 63;
  const int rg   = wid & 3;        // row group (32 rows)
  const int mh   = wid >> 2;       // M-half
  const int g0   = blockIdx.x*128 + rg*32;
  const int r15  = lane & 15;
  const int hi   = lane >> 4;
  const int ko   = hi << 3;
  const int rb   = hi << 2;
  const int ntb  = mh << 2;
  const int nzb  = mh << 1;
  const f32x4 z4 = {0.f,0.f,0.f,0.f};

  // ---- async stage packed weights -> LDS (global_load_lds, width 16) ----
  {
    auto* gsrc = (const __attribute__((address_space(1))) char*)packed;
    auto* ldst = (__attribute__((address_space(3))) char*)pk_sh;
    #pragma unroll
    for (int it = 0; it < 16; ++it){
      int off = it*8192 + wid*1024;
      __builtin_amdgcn_global_load_lds(
        (const __attribute__((address_space(1))) unsigned*)(gsrc + off + lane*16),
        (__attribute__((address_space(3))) unsigned*)(ldst + off),
        16, 0, 0);
    }
  }

  // ---- A-fragments (latency hides under staging) ----
  s16x8 fz0[2], fz1[2], fac[2], fc0[2], fc1[2], frw[2];
  #pragma unroll
  for (int s = 0; s < 2; ++s){
    const int ar = g0 + s*16 + r15;
    fz0[s] = ldA_g(z + (size_t)ar*64,            ko, 64);
    fz1[s] = ldA_g(z + (size_t)ar*64 + 32,       ko, 32);
    fac[s] = ldA_g(action + (size_t)ar*32,       ko, 32);
    fc0[s] = ldA_g(control + (size_t)ar*64,      ko, 64);
    fc1[s] = ldA_g(control + (size_t)ar*64 + 32, ko, 32);
    frw[s] = ldA_g(rw + (size_t)ar*16,           ko, 16);
  }

  // ---- fb . control (f32, independent of staging) ----
  if (mh == 0){
    #pragma unroll
    for (int s = 0; s < 2; ++s){
      const int ar = g0 + s*16 + r15;
      const float* cp = control + (size_t)ar*64;
      float4 c0a = *(const float4*)(cp + ko);
      float4 c0b = *(const float4*)(cp + ko + 4);
      float4 c1a = *(const float4*)(cp + 32 + ko);
      float4 c1b = *(const float4*)(cp + 32 + ko + 4);
      float4 f0a = *(const float4*)(formb + ko);
      float4 f0b = *(const float4*)(formb + ko + 4);
      float4 f1a = *(const float4*)(formb + 32 + ko);
      float4 f1b = *(const float4*)(formb + 32 + ko + 4);
      float fbp = c0a.x*f0a.x + c0a.y*f0a.y + c0a.z*f0a.z + c0a.w*f0a.w
                + c0b.x*f0b.x + c0b.y*f0b.y + c0b.z*f0b.z + c0b.w*f0b.w
                + c1a.x*f1a.x + c1a.y*f1a.y + c1a.z*f1a.z + c1a.w*f1a.w
                + c1b.x*f1b.x + c1b.y*f1b.y + c1b.z*f1b.z + c1b.w*f1b.w;
      fbp += __shfl_xor(fbp, 16);
      fbp += __shfl_xor(fbp, 32);
      if (lane < 16) ex[rg*32 + s*16 + r15][48] = fbp;
    }
  }

  const float inv_f = sig[0], inv_c = sig[1];

  __syncthreads();                 // staging (+vmcnt drain) complete
  const unsigned short* pk = pk_sh;

  // ---- qW = z@Weqk + bqk (dual-subtile) ----
  f32x4 qw[2][4];
  {
    #pragma unroll
    for (int s = 0; s < 2; ++s)
      #pragma unroll
      for (int nl = 0; nl < 4; ++nl) qw[s][nl] = z4;
    #pragma unroll
    for (int kt = 0; kt < 2; ++kt){
      #pragma unroll
      for (int nl = 0; nl < 4; ++nl){
        s16x8 bfr = ldB(pk, OFF_WEQK + kt*8 + ntb + nl, lane);
        qw[0][nl] = MF(kt == 0 ? fz0[0] : fz1[0], bfr, qw[0][nl]);
        qw[1][nl] = MF(kt == 0 ? fz0[1] : fz1[1], bfr, qw[1][nl]);
      }
    }
    const float* bqk = prep + 16384;
    #pragma unroll
    for (int nl = 0; nl < 4; ++nl){
      float bv = bqk[(ntb + nl)*16 + r15];
      #pragma unroll
      for (int s = 0; s < 2; ++s)
        #pragma unroll
        for (int j = 0; j < 4; ++j) qw[s][nl][j] += bv;
    }
  }

  // ---- hw = inv_c*wvoc + inv_f*(control@WvofT)  (dual-subtile) ----
  f32x4 hw[2][4];
  {
    #pragma unroll
    for (int s = 0; s < 2; ++s)
      #pragma unroll
      for (int nl = 0; nl < 4; ++nl) hw[s][nl] = z4;
    #pragma unroll
    for (int kt = 0; kt < 2; ++kt){
      #pragma unroll
      for (int nl = 0; nl < 4; ++nl){
        s16x8 bfr = ldB(pk, OFF_WVOFT + kt*8 + ntb + nl, lane);
        hw[0][nl] = MF(kt == 0 ? fc0[0] : fc1[0], bfr, hw[0][nl]);
        hw[1][nl] = MF(kt == 0 ? fc0[1] : fc1[1], bfr, hw[1][nl]);
      }
    }
    const float* wvoc = prep + 16512;
    #pragma unroll
    for (int nl = 0; nl < 4; ++nl){
      float wvc = inv_c*wvoc[(ntb + nl)*16 + r15];
      #pragma unroll
      for (int s = 0; s < 2; ++s)
        #pragma unroll
        for (int j = 0; j < 4; ++j) hw[s][nl][j] = wvc + inv_f*hw[s][nl][j];
    }
  }

  // ---- tokens ----
  float st[3][2][4], hs[3][2][4];
  {
    s16x8 afA[3][2] = {{fac[0],fac[1]},{fz0[0],fz0[1]},{fz1[0],fz1[1]}};
    s16x8 afAz[1][2] = {{fac[0],fac[1]}};
    token_dot2<3,1>(pk, OFF_ACTX, afA, OFF_ACTZ, afAz, act_bx, lane, ntb, nzb, qw, hw, st[0], hs[0]);
  }
  {
    s16x8 afC[4][2] = {{fc0[0],fc0[1]},{fc1[0],fc1[1]},{fz0[0],fz0[1]},{fz1[0],fz1[1]}};
    s16x8 afCz[2][2] = {{fc0[0],fc0[1]},{fc1[0],fc1[1]}};
    token_dot2<4,2>(pk, OFF_CTLX, afC, OFF_CTLZ, afCz, ctl_bx, lane, ntb, nzb, qw, hw, st[1], hs[1]);
  }
  {
    s16x8 afH[3][2] = {{frw[0],frw[1]},{fz0[0],fz0[1]},{fz1[0],fz1[1]}};
    s16x8 afHz[1][2] = {{frw[0],frw[1]}};
    token_dot2<3,1>(pk, OFF_CHTX, afH, OFF_CHTZ, afHz, cht_bx, lane, ntb, nzb, qw, hw, st[2], hs[2]);
  }

  // ---- 2-step partial reduce (4-lane groups), then LDS exchange ----
  #pragma unroll
  for (int m = 1; m < 4; m <<= 1)
    #pragma unroll
    for (int t = 0; t < 3; ++t)
      #pragma unroll
      for (int s = 0; s < 2; ++s)
        #pragma unroll
        for (int j = 0; j < 4; ++j){
          st[t][s][j] += __shfl_xor(st[t][s][j], m);
          hs[t][s][j] += __shfl_xor(hs[t][s][j], m);
        }
  if ((r15 & 3) == 0){
    int gi = r15 >> 2;
    #pragma unroll
    for (int s = 0; s < 2; ++s)
      #pragma unroll
      for (int t = 0; t < 3; ++t)
        #pragma unroll
        for (int j = 0; j < 4; ++j){
          int row = rg*32 + s*16 + rb + j;
          ex[row][t*8 + mh*4 + gi]      = st[t][s][j];
          ex[row][24 + t*8 + mh*4 + gi] = hs[t][s][j];
        }
  }
  __syncthreads();

  // ---- merge phase: one thread per row ----
  if (tid < 128){
    const int row = tid;
    float sv[3], hv[3];
    #pragma unroll
    for (int t = 0; t < 3; ++t){
      float a = 0.f, h = 0.f;
      #pragma unroll
      for (int i = 0; i < 8; ++i){
        a += ex[row][t*8 + i];
        h += ex[row][24 + t*8 + i];
      }
      sv[t] = a; hv[t] = h;
    }
    float mx = fmaxf(sv[0], fmaxf(sv[1], sv[2]));
    float e0 = __expf(sv[0]-mx), e1 = __expf(sv[1]-mx), e2 = __expf(sv[2]-mx);
    float inv = __builtin_amdgcn_rcpf(e0 + e1 + e2);
    float tot = (e0*hv[0] + e1*hv[1] + e2*hv[2])*inv + ex[row][48] + consb[0];
    out[blockIdx.x*128 + row] = tot;
  }
}

extern "C" void kernel_launch(void* const* d_in, const int* in_sizes, int n_in,
                              void* d_out, int out_size, void* d_ws, size_t ws_size,
                              hipStream_t stream)
{
  const float* z      = (const float*)d_in[0];
  const float* action = (const float*)d_in[1];
  const float* rw     = (const float*)d_in[2];
  const float* control= (const float*)d_in[3];
  const float* actWx  = (const float*)d_in[4];
  const float* actbx  = (const float*)d_in[5];
  const float* actWz  = (const float*)d_in[6];
  const float* ctlWx  = (const float*)d_in[7];
  const float* ctlbx  = (const float*)d_in[8];
  const float* ctlWz  = (const float*)d_in[9];
  const float* chtWx  = (const float*)d_in[10];
  const float* chtbx  = (const float*)d_in[11];
  const float* chtWz  = (const float*)d_in[12];
  const float* We     = (const float*)d_in[13];
  const float* be     = (const float*)d_in[14];
  const float* Wq     = (const float*)d_in[15];
  const float* Wk     = (const float*)d_in[16];
  const float* Wv     = (const float*)d_in[17];
  const float* Wo     = (const float*)d_in[18];
  const float* consW  = (const float*)d_in[19];
  const float* consb  = (const float*)d_in[20];
  const float* formW  = (const float*)d_in[21];
  const float* formb  = (const float*)d_in[22];
  float* out = (float*)d_out;

  unsigned short* packed = (unsigned short*)d_ws;
  float* sig  = (float*)((char*)d_ws + SIG_OFF);
  float* prep = (float*)((char*)d_ws + PREP_OFF);

  hipLaunchKernelGGL(prep_all, dim3(227), dim3(256), 0, stream,
                     We, be, Wq, Wk, Wv, Wo, consW, formW,
                     actWx, ctlWx, chtWx, actWz, ctlWz, chtWz,
                     packed, prep, sig);
  hipLaunchKernelGGL(reward_main, dim3(256), dim3(512), 0, stream,
                     z, action, rw, control, actbx, ctlbx, chtbx,
                     consb, formb, packed, prep, sig, out);
}